// Round 2
// baseline (1727.315 us; speedup 1.0000x reference)
//
#include <hip/hip_runtime.h>

typedef unsigned short u16;
typedef unsigned int   u32;
typedef unsigned long long u64;

typedef __attribute__((ext_vector_type(8))) short bf16x8;
typedef __attribute__((ext_vector_type(4))) float f32x4;

typedef __attribute__((address_space(1))) void gvoid_t;
typedef __attribute__((address_space(3))) void lvoid_t;

#define DEVI static __device__ __forceinline__

DEVI float bf2f(u16 u){ union{u32 i; float f;} w; w.i = ((u32)u)<<16; return w.f; }
DEVI u16 f2bf(float f){ union{float f; u32 i;} u; u.f = f; u32 r = u.i + 0x7fffu + ((u.i>>16)&1u); return (u16)(r>>16); }

DEVI void gl_lds16(const void* g, void* l){
  // global -> LDS direct, 16B per lane; LDS dest = wave-uniform base + lane*16
  __builtin_amdgcn_global_load_lds((gvoid_t*)(u64)g, (lvoid_t*)(u32)(u64)l, 16, 0, 0);
}

// ---------------- transpose + f32->bf16 convert: W[K][N] -> WT[N][K] ----------------
__global__ void kT(const float* __restrict__ W, u16* __restrict__ WT, int K, int N){
  __shared__ float tile[32][33];
  const int bn = blockIdx.x*32, bk = blockIdx.y*32;
  const int x = threadIdx.x & 31, y = threadIdx.x >> 5;
#pragma unroll
  for(int i=0;i<4;i++)
    tile[y + i*8][x] = W[(size_t)(bk + y + i*8)*N + bn + x];
  __syncthreads();
  const int tid = threadIdx.x;
#pragma unroll
  for(int it=0; it<2; it++){
    int idx = it*256 + tid;
    int n = idx >> 4, c = (idx & 15)*2;
    ushort2 val;
    val.x = f2bf(tile[c][n]);
    val.y = f2bf(tile[c+1][n]);
    *(ushort2*)(WT + (size_t)(bn + n)*K + bk + c) = val;
  }
}

// ---------------- bf16 transpose of V slab: qkv[t][5120+c] -> vT[c][t] ----------------
__global__ void kvt(const u16* __restrict__ qkv, u16* __restrict__ vT){
  __shared__ u16 tile[32][33];
  const int bt = blockIdx.x*32, bc = blockIdx.y*32;
  const int x = threadIdx.x & 31, y = threadIdx.x >> 5;
#pragma unroll
  for(int i=0;i<4;i++)
    tile[y + i*8][x] = qkv[(size_t)(bt + y + i*8)*6144 + 5120 + bc + x];
  __syncthreads();
#pragma unroll
  for(int i=0;i<4;i++)
    vT[(size_t)(bc + y + i*8)*2048 + bt + x] = tile[x][y + i*8];
}

// ---------------- RMSNorm: f32 in -> bf16 out (row = 4096) ----------------
__global__ void krms(const float* __restrict__ x, const float* __restrict__ w, u16* __restrict__ o){
  const int row = blockIdx.x, tid = threadIdx.x;
  const float* xr = x + (size_t)row*4096;
  float4 v[4];
  float ss = 0.f;
#pragma unroll
  for(int i=0;i<4;i++){
    v[i] = ((const float4*)xr)[i*256 + tid];
    ss += v[i].x*v[i].x + v[i].y*v[i].y + v[i].z*v[i].z + v[i].w*v[i].w;
  }
#pragma unroll
  for(int off=1; off<64; off<<=1) ss += __shfl_xor(ss, off);
  __shared__ float red[4];
  if((tid&63)==0) red[tid>>6] = ss;
  __syncthreads();
  float tot = red[0]+red[1]+red[2]+red[3];
  float rr = rsqrtf(tot*(1.f/4096.f) + 1e-5f);
  ushort4* op = (ushort4*)(o + (size_t)row*4096);
#pragma unroll
  for(int i=0;i<4;i++){
    float4 wv = ((const float4*)w)[i*256 + tid];
    ushort4 pk;
    pk.x = f2bf(v[i].x*rr*wv.x);
    pk.y = f2bf(v[i].y*rr*wv.y);
    pk.z = f2bf(v[i].z*rr*wv.z);
    pk.w = f2bf(v[i].w*rr*wv.w);
    op[i*256 + tid] = pk;
  }
}

// ---------------- RoPE in-place on q,k parts of qkv[2048][6144] ----------------
__global__ void krope(u16* qkv){
  const int g = blockIdx.x*256 + threadIdx.x;   // 2048*40*64 total
  const int t = g / 2560;
  const int r = g % 2560;
  const int hh = r >> 6, i = r & 63;
  const size_t base = (size_t)t*6144 + (hh < 32 ? hh*128 : 4096 + (hh-32)*128) + 2*i;
  const float inv = exp2f(-(float)i * (13.287712379549449f/64.f));  // theta^(-i/64)
  const float ang = (float)t * inv;
  float s, c;
  sincosf(ang, &s, &c);
  float x1 = bf2f(qkv[base]), x2 = bf2f(qkv[base+1]);
  qkv[base]   = f2bf(x1*c - x2*s);
  qkv[base+1] = f2bf(x1*s + x2*c);
}

// ---------------- GEMM: C[M][N] = A[M][K](bf16) @ Bt[N][K](bf16)^T ----------------
// MODE 0: C bf16.  MODE 1: C f32 = acc + aux_f32.  MODE 2: C bf16 = silu(acc)*aux_bf16.
template<int MODE>
__launch_bounds__(256, 2)
__global__ void kgemm(const u16* __restrict__ A, const u16* __restrict__ Bt,
                      void* __restrict__ C, const void* __restrict__ aux,
                      int M, int N, int K)
{
  __shared__ u16 Alds[128*64];
  __shared__ u16 Blds[128*64];
  const int tid = threadIdx.x;
  const int wid = tid >> 6, l = tid & 63;
  const int l4 = l & 15, gg = l >> 4;
  const int mb = blockIdx.y, nb = blockIdx.x;
  const int wr = (wid >> 1)*64, wc = (wid & 1)*64;

  f32x4 zero = {0.f,0.f,0.f,0.f};
  f32x4 acc[4][4];
#pragma unroll
  for(int m=0;m<4;m++)
#pragma unroll
    for(int n=0;n<4;n++) acc[m][n] = zero;

  const int srow = wid*8 + (l>>3);                 // 0..31 per 32-row chunk
  const int sblk = (l&7) ^ ((l>>3)&7);             // pre-swizzled source block
  const u16* Asrc = A  + (size_t)(mb*128 + srow)*K + sblk*8;
  const u16* Bsrc = Bt + (size_t)(nb*128 + srow)*K + sblk*8;
  const int sw = (l4 & 7) << 4;

  for(int kt=0; kt<K; kt+=64){
#pragma unroll
    for(int i=0;i<4;i++){
      gl_lds16(Asrc + (size_t)i*32*K + kt, Alds + i*2048 + wid*512);
      gl_lds16(Bsrc + (size_t)i*32*K + kt, Blds + i*2048 + wid*512);
    }
    __syncthreads();
#pragma unroll
    for(int kk=0;kk<2;kk++){
      bf16x8 af[4], bfr[4];
#pragma unroll
      for(int m=0;m<4;m++){
        int row = wr + m*16 + l4;
        af[m] = *(const bf16x8*)((const char*)Alds + row*128 + ((((kk<<2)+gg)<<4) ^ sw));
      }
#pragma unroll
      for(int n=0;n<4;n++){
        int row = wc + n*16 + l4;
        bfr[n] = *(const bf16x8*)((const char*)Blds + row*128 + ((((kk<<2)+gg)<<4) ^ sw));
      }
#pragma unroll
      for(int m=0;m<4;m++)
#pragma unroll
        for(int n=0;n<4;n++)
          acc[m][n] = __builtin_amdgcn_mfma_f32_16x16x32_bf16(af[m], bfr[n], acc[m][n], 0,0,0);
    }
    __syncthreads();
  }

#pragma unroll
  for(int m=0;m<4;m++){
#pragma unroll
    for(int r=0;r<4;r++){
      int grow = mb*128 + wr + m*16 + gg*4 + r;
#pragma unroll
      for(int n=0;n<4;n++){
        int gcol = nb*128 + wc + n*16 + l4;
        size_t idx = (size_t)grow*N + gcol;
        float v = acc[m][n][r];
        if(MODE == 0){
          ((u16*)C)[idx] = f2bf(v);
        } else if(MODE == 1){
          ((float*)C)[idx] = v + ((const float*)aux)[idx];
        } else {
          float u = bf2f(((const u16*)aux)[idx]);
          float s = v / (1.f + __expf(-v));
          ((u16*)C)[idx] = f2bf(s * u);
        }
      }
    }
  }
}

// ---------------- causal GQA flash attention ----------------
// grid (32 q-tiles, 32 heads), 256 threads (4 waves x 16 q-rows each)
__launch_bounds__(256, 2)
__global__ void kattn(const u16* __restrict__ qkv, const u16* __restrict__ vT,
                      u16* __restrict__ out)
{
  __shared__ u16 Klds[32*128];      // [kv][d], XOR-swizzled 16B blocks
  __shared__ u16 Vlds[128*32];      // [d][kv], XOR-swizzled 16B blocks
  __shared__ u16 P[4][16*32];       // per-wave P tile
  const int qt = blockIdx.x, h = blockIdx.y;
  const int kvh = h >> 2;
  const int tid = threadIdx.x, wid = tid >> 6, l = tid & 63;
  const int l4 = l & 15, gg = l >> 4;
  const int qbase = qt*64 + wid*16;

  bf16x8 qf[4];
  {
    const u16* qp = qkv + (size_t)(qbase + l4)*6144 + h*128 + gg*8;
#pragma unroll
    for(int kc=0;kc<4;kc++) qf[kc] = *(const bf16x8*)(qp + kc*32);
  }
  f32x4 o[8];
  f32x4 zero = {0.f,0.f,0.f,0.f};
#pragma unroll
  for(int nb=0;nb<8;nb++) o[nb] = zero;
  float m[4]  = {-__builtin_inff(),-__builtin_inff(),-__builtin_inff(),-__builtin_inff()};
  float ls[4] = {0.f,0.f,0.f,0.f};

  const int nkt = qt*2 + 2;
  for(int kt=0; kt<nkt; kt++){
    __syncthreads();
    // stage K (swizzled row-major) and V (from vT, swizzled [d][kv])
#pragma unroll
    for(int it=0; it<2; it++){
      int idx = it*256 + tid;
      int r = idx >> 4, b = idx & 15;
      const u16* ks = qkv + (size_t)(kt*32 + r)*6144 + 4096 + kvh*128 + b*8;
      bf16x8 kvec = *(const bf16x8*)ks;
      *(bf16x8*)((char*)Klds + r*256 + ((b*16) ^ ((r&7)<<4))) = kvec;

      int d = idx >> 2, blk = idx & 3;
      const u16* vs = vT + (size_t)(kvh*128 + d)*2048 + kt*32 + blk*8;
      bf16x8 vvec = *(const bf16x8*)vs;
      *(bf16x8*)((char*)Vlds + d*64 + ((blk*16) ^ ((d&3)<<4))) = vvec;
    }
    __syncthreads();

    if(kt*32 <= qbase + 15){   // wave-uniform: skip fully-masked tiles
      f32x4 s0 = zero, s1 = zero;
#pragma unroll
      for(int kc=0;kc<4;kc++){
        int co = (kc*64 + gg*16) ^ ((l4&7)<<4);
        bf16x8 k0 = *(const bf16x8*)((char*)Klds + l4*256 + co);
        bf16x8 k1 = *(const bf16x8*)((char*)Klds + (l4+16)*256 + co);
        s0 = __builtin_amdgcn_mfma_f32_16x16x32_bf16(qf[kc], k0, s0, 0,0,0);
        s1 = __builtin_amdgcn_mfma_f32_16x16x32_bf16(qf[kc], k1, s1, 0,0,0);
      }
      const float scale = 0.08838834764831845f;
      const int kv0 = kt*32 + l4;
      float p0[4], p1[4], al[4];
#pragma unroll
      for(int r=0;r<4;r++){
        int qrow = qbase + gg*4 + r;
        float a  = (kv0      <= qrow) ? s0[r]*scale : -__builtin_inff();
        float b2 = (kv0 + 16 <= qrow) ? s1[r]*scale : -__builtin_inff();
        float mx = fmaxf(a, b2);
        mx = fmaxf(mx, __shfl_xor(mx,1));
        mx = fmaxf(mx, __shfl_xor(mx,2));
        mx = fmaxf(mx, __shfl_xor(mx,4));
        mx = fmaxf(mx, __shfl_xor(mx,8));
        float mn = fmaxf(m[r], mx);
        float alpha = __expf(m[r]-mn);
        float e0 = __expf(a-mn), e1 = __expf(b2-mn);
        float ts = e0+e1;
        ts += __shfl_xor(ts,1); ts += __shfl_xor(ts,2);
        ts += __shfl_xor(ts,4); ts += __shfl_xor(ts,8);
        ls[r] = ls[r]*alpha + ts;
        m[r] = mn; al[r] = alpha;
        p0[r] = e0; p1[r] = e1;
      }
#pragma unroll
      for(int nb=0;nb<8;nb++)
#pragma unroll
        for(int r=0;r<4;r++) o[nb][r] *= al[r];

      u16* Pw = P[wid];
#pragma unroll
      for(int r=0;r<4;r++){
        Pw[(gg*4+r)*32 + l4]      = f2bf(p0[r]);
        Pw[(gg*4+r)*32 + 16 + l4] = f2bf(p1[r]);
      }
      bf16x8 pa = *(const bf16x8*)(Pw + l4*32 + gg*8);
#pragma unroll
      for(int nb=0;nb<8;nb++){
        int d = nb*16 + l4;
        bf16x8 bv = *(const bf16x8*)((char*)Vlds + d*64 + ((gg*16) ^ ((d&3)<<4)));
        o[nb] = __builtin_amdgcn_mfma_f32_16x16x32_bf16(pa, bv, o[nb], 0,0,0);
      }
    }
  }
#pragma unroll
  for(int r=0;r<4;r++){
    float inv = 1.f/(ls[r] + 1e-6f);
    u16* dst = out + (size_t)(qbase + gg*4 + r)*4096 + h*128;
#pragma unroll
    for(int nb=0;nb<8;nb++) dst[nb*16 + l4] = f2bf(o[nb][r]*inv);
  }
}

// ---------------- launcher ----------------
extern "C" void kernel_launch(void* const* d_in, const int* in_sizes, int n_in,
                              void* d_out, int out_size, void* d_ws, size_t ws_size,
                              hipStream_t stream)
{
  (void)in_sizes; (void)n_in; (void)out_size; (void)ws_size;
  const float* x      = (const float*)d_in[0];
  const float* ln_w   = (const float*)d_in[1];
  const float* ffln_w = (const float*)d_in[2];
  const float* wq = (const float*)d_in[3];
  const float* wk = (const float*)d_in[4];
  const float* wv = (const float*)d_in[5];
  const float* wo = (const float*)d_in[6];
  const float* wg = (const float*)d_in[7];
  const float* w1 = (const float*)d_in[8];
  const float* w2 = (const float*)d_in[9];

  // Workspace layout (single reusable weight buffer keeps total ~305 MB)
  char* ws = (char*)d_ws;
  u16* wT    = (u16*)ws;  ws += (size_t)22016*4096*2;  // reused for all weight transposes
  u16* vT    = (u16*)ws;  ws += (size_t)1024*2048*2;
  u16* hbuf  = (u16*)ws;  ws += (size_t)2048*4096*2;   // reused as attno
  u16* qkv   = (u16*)ws;  ws += (size_t)2048*6144*2;   // reused as gbuf
  float* r1  = (float*)ws; ws += (size_t)2048*4096*4;
  u16* up    = (u16*)ws;  ws += (size_t)2048*11008*2;  // MODE-2 gemm rewrites in place
  u16* attno = hbuf;
  u16* gbuf  = qkv;

  dim3 blk(256);

  // ---- stage 1: x -> rmsnorm -> qkv ----
  kT<<<dim3(128,128),blk,0,stream>>>(wq, wT,                      4096, 4096);
  kT<<<dim3(32, 128),blk,0,stream>>>(wk, wT + (size_t)4096*4096,  4096, 1024);
  kT<<<dim3(32, 128),blk,0,stream>>>(wv, wT + (size_t)5120*4096,  4096, 1024);
  krms<<<2048, blk, 0, stream>>>(x, ln_w, hbuf);
  kgemm<0><<<dim3(48,16), blk, 0, stream>>>(hbuf, wT, qkv, nullptr, 2048, 6144, 4096);
  krope<<<20480, blk, 0, stream>>>(qkv);
  kvt<<<dim3(64,32), blk, 0, stream>>>(qkv, vT);

  // ---- stage 2: attention + wo projection + residual ----
  kattn<<<dim3(32,32), blk, 0, stream>>>(qkv, vT, attno);
  kT<<<dim3(128,128),blk,0,stream>>>(wo, wT, 4096, 4096);
  kgemm<1><<<dim3(32,16), blk, 0, stream>>>(attno, wT, r1, x, 2048, 4096, 4096);

  // ---- stage 3: FFN ----
  krms<<<2048, blk, 0, stream>>>(r1, ffln_w, gbuf);
  kT<<<dim3(344,128),blk,0,stream>>>(wg, wT,                      4096, 11008);
  kT<<<dim3(344,128),blk,0,stream>>>(w1, wT + (size_t)11008*4096, 4096, 11008);
  kgemm<0><<<dim3(86,16), blk, 0, stream>>>(gbuf, wT + (size_t)11008*4096, up, nullptr, 2048, 11008, 4096);
  kgemm<2><<<dim3(86,16), blk, 0, stream>>>(gbuf, wT, up, up, 2048, 11008, 4096);
  kT<<<dim3(128,344),blk,0,stream>>>(w2, wT, 11008, 4096);
  kgemm<1><<<dim3(32,16), blk, 0, stream>>>(up, wT, (float*)d_out, r1, 2048, 4096, 11008);
}